// Round 5
// baseline (62.305 us; speedup 1.0000x reference)
//
#include <hip/hip_runtime.h>

#define NC 1024
#define NS 32
#define DD 512
#define MARGIN 0.3f

// One block per class, 256 threads (R2's proven codegen shape: the 128 KB
// class tile is register-resident, each HBM byte read exactly once).
// g = t>>7 picks sample parity (rows s = 2j+g), col4 = t&127 the thread's
// float4 column; consecutive lanes -> consecutive float4s (coalesced).
// Final mean over classes is fused: last block to finish reduces the
// per-class losses (counter in d_ws zeroed by a memset node each call).
//
// CRITICAL codegen note (rule #20): every array index must be a parse-time
// constant. R3/R4 used a reduction helper whose inner-loop bound was a
// runtime variable of the outer loop -> SROA failed -> p/n/apc/ndc demoted
// to scratch (VGPR_Count 40/72, ~100us). All loops below have literal bounds.
__global__ __launch_bounds__(256) void ccl_fused(const float* __restrict__ emb,
                                                 float* __restrict__ cls,
                                                 unsigned* __restrict__ cnt,
                                                 float* __restrict__ out) {
    const int c = blockIdx.x;
    const int t = threadIdx.x;
    const int g = t >> 7;
    const int col4 = t & 127;
    const int lane = t & 63;
    const int wv = t >> 6;
    const float4* posv = (const float4*)(emb + (size_t)c * (2 * NS * DD));
    const float4* negv = posv + NS * DD / 4;

    __shared__ float4 s_part[2][128];
    __shared__ float s_wap[4][16];
    __shared__ float s_wnd[4][16];
    __shared__ float s_fin[4];
    __shared__ unsigned s_old;

    // ---- load: 16 pos rows then 16 neg rows (rows s = 2j+g) ----
    float4 p[16], n[16];
#pragma unroll
    for (int j = 0; j < 16; ++j) p[j] = posv[(2 * j + g) * (DD / 4) + col4];
#pragma unroll
    for (int j = 0; j < 16; ++j) n[j] = negv[(2 * j + g) * (DD / 4) + col4];

    // ---- anchor: thread-local column sum over 16 rows, LDS combine ----
    float4 acc = p[0];
#pragma unroll
    for (int j = 1; j < 16; ++j) {
        acc.x += p[j].x; acc.y += p[j].y; acc.z += p[j].z; acc.w += p[j].w;
    }
    s_part[g][col4] = acc;
    __syncthreads();
    float4 a;
    {
        float4 x0 = s_part[0][col4], x1 = s_part[1][col4];
        a.x = (x0.x + x1.x) * (1.f / NS);
        a.y = (x0.y + x1.y) * (1.f / NS);
        a.z = (x0.z + x1.z) * (1.f / NS);
        a.w = (x0.w + x1.w) * (1.f / NS);
    }

    // ---- per-(sample, column) squared-diff partials ----
    float apc[16], ndc[16];
#pragma unroll
    for (int j = 0; j < 16; ++j) {
        float dx = p[j].x - a.x, dy = p[j].y - a.y, dz = p[j].z - a.z, dw = p[j].w - a.w;
        apc[j] = dx * dx + dy * dy + dz * dz + dw * dw;
        dx = n[j].x - a.x; dy = n[j].y - a.y; dz = n[j].z - a.z; dw = n[j].w - a.w;
        ndc[j] = dx * dx + dy * dy + dz * dz + dw * dw;
    }

    // ---- halving butterfly across the wave's 64 columns ----
    // Step mask m pairs lanes l, l^m; the (l&m)-set lane keeps the hi half.
    // All bounds are LITERALS so indices stay compile-time static.
#define BSTEP(arr, m, half)                                        \
    {                                                              \
        _Pragma("unroll")                                          \
        for (int i = 0; i < (half); ++i) {                         \
            float lo = arr[i], hi = arr[i + (half)];               \
            float send = (lane & (m)) ? lo : hi;                   \
            float recv = __shfl_xor(send, (m));                    \
            arr[i] = (lane & (m)) ? (hi + recv) : (lo + recv);     \
        }                                                          \
    }
    BSTEP(apc, 1, 8) BSTEP(apc, 2, 4) BSTEP(apc, 4, 2) BSTEP(apc, 8, 1)
    BSTEP(ndc, 1, 8) BSTEP(ndc, 2, 4) BSTEP(ndc, 4, 2) BSTEP(ndc, 8, 1)
#undef BSTEP
    // lane holds element j = bitrev4(lane&15) summed over its 16-lane group;
    // fold the four groups of the wave:
    float rap = apc[0];
    rap += __shfl_xor(rap, 16);
    rap += __shfl_xor(rap, 32);
    float rnd = ndc[0];
    rnd += __shfl_xor(rnd, 16);
    rnd += __shfl_xor(rnd, 32);
    if (lane < 16) {
        const int jm = ((lane & 1) << 3) | ((lane & 2) << 1) | ((lane & 4) >> 1) | ((lane & 8) >> 3);
        s_wap[wv][jm] = rap;
        s_wnd[wv][jm] = rnd;
    }
    __syncthreads();

    // ---- per-class min + hinge (lanes 0-31 of wave 0) ----
    if (t < NS) {
        const int sg = t & 1, sj = t >> 1;  // sample s = 2*sj + sg
        float ap = s_wap[2 * sg][sj] + s_wap[2 * sg + 1][sj];
        float nd = s_wnd[2 * sg][sj] + s_wnd[2 * sg + 1][sj];
        float an = nd;
#pragma unroll
        for (int m = 1; m < 32; m <<= 1) an = fminf(an, __shfl_xor(an, m));
        float l = fmaxf(ap - an + MARGIN, 0.f);
#pragma unroll
        for (int m = 1; m < 32; m <<= 1) l += __shfl_xor(l, m);
        if (t == 0) {
            __hip_atomic_store(&cls[c], l, __ATOMIC_RELAXED, __HIP_MEMORY_SCOPE_AGENT);
            s_old = __hip_atomic_fetch_add(cnt, 1u, __ATOMIC_ACQ_REL, __HIP_MEMORY_SCOPE_AGENT);
        }
    }
    __syncthreads();

    // ---- last block computes the deterministic fixed-order mean ----
    if (s_old == NC - 1) {
        float v = __hip_atomic_load(&cls[t], __ATOMIC_ACQUIRE, __HIP_MEMORY_SCOPE_AGENT) +
                  __hip_atomic_load(&cls[t + 256], __ATOMIC_ACQUIRE, __HIP_MEMORY_SCOPE_AGENT) +
                  __hip_atomic_load(&cls[t + 512], __ATOMIC_ACQUIRE, __HIP_MEMORY_SCOPE_AGENT) +
                  __hip_atomic_load(&cls[t + 768], __ATOMIC_ACQUIRE, __HIP_MEMORY_SCOPE_AGENT);
#pragma unroll
        for (int m = 1; m < 64; m <<= 1) v += __shfl_xor(v, m);
        if (lane == 0) s_fin[wv] = v;
        __syncthreads();
        if (t == 0)
            out[0] = (s_fin[0] + s_fin[1] + s_fin[2] + s_fin[3]) * (1.f / NC);
    }
}

extern "C" void kernel_launch(void* const* d_in, const int* in_sizes, int n_in,
                              void* d_out, int out_size, void* d_ws, size_t ws_size,
                              hipStream_t stream) {
    const float* emb = (const float*)d_in[0];       // (2*NC*NS, DD) f32
    unsigned* cnt = (unsigned*)d_ws;                // completion counter
    float* cls = (float*)((char*)d_ws + 256);       // NC per-class losses
    float* out = (float*)d_out;                     // 1 float
    hipMemsetAsync(cnt, 0, 4, stream);              // zero counter each call
    ccl_fused<<<NC, 256, 0, stream>>>(emb, cls, cnt, out);
}

// Round 6
// 29.416 us; speedup vs baseline: 2.1181x; 2.1181x over previous
//
#include <hip/hip_runtime.h>

#define NC 1024
#define NS 32
#define DD 512
#define MARGIN 0.3f

// Kernel 1: one block per class, 512 threads, thread t owns scalar column t.
// All 32 pos + 32 neg rows of that column are loaded into registers (64
// independent coalesced dword loads -> max MLP, each HBM byte read once).
// Anchor is thread-local (mean over the thread's own 32 pos values): no LDS
// round-trip, no barrier until the final cross-wave combine.
//
// Codegen rule #20: every array index below is compile-time static (literal
// loop bounds only) so p[]/n[] stay in VGPRs, not scratch.
__global__ __launch_bounds__(512) void ccl_per_class(const float* __restrict__ emb,
                                                     float* __restrict__ cls) {
    const int c = blockIdx.x;
    const int t = threadIdx.x;
    const int lane = t & 63;
    const int wv = t >> 6;
    const float* pos = emb + (size_t)c * (2 * NS * DD);
    const float* neg = pos + NS * DD;

    __shared__ float s_wap[8][32];
    __shared__ float s_wnd[8][32];

    // ---- load entire column: 32 pos then 32 neg (all issued up front) ----
    float p[32], n[32];
#pragma unroll
    for (int s = 0; s < 32; ++s) p[s] = pos[s * DD + t];
#pragma unroll
    for (int s = 0; s < 32; ++s) n[s] = neg[s * DD + t];

    // ---- thread-local anchor for this column ----
    float a = 0.f;
#pragma unroll
    for (int s = 0; s < 32; ++s) a += p[s];
    a *= (1.f / NS);

    // ---- square diffs in place ----
#pragma unroll
    for (int s = 0; s < 32; ++s) { float d = p[s] - a; p[s] = d * d; }
#pragma unroll
    for (int s = 0; s < 32; ++s) { float d = n[s] - a; n[s] = d * d; }

    // ---- halving butterfly across the wave's 64 columns ----
    // Step mask m pairs lanes l, l^m; the (l&m)-set lane keeps the hi half.
    // Literal bounds; static indices.
#define BSTEP(arr, m, half)                                        \
    {                                                              \
        _Pragma("unroll")                                          \
        for (int i = 0; i < (half); ++i) {                         \
            float lo = arr[i], hi = arr[i + (half)];               \
            float send = (lane & (m)) ? lo : hi;                   \
            float recv = __shfl_xor(send, (m));                    \
            arr[i] = (lane & (m)) ? (hi + recv) : (lo + recv);     \
        }                                                          \
    }
    BSTEP(p, 1, 16) BSTEP(p, 2, 8) BSTEP(p, 4, 4) BSTEP(p, 8, 2) BSTEP(p, 16, 1)
    BSTEP(n, 1, 16) BSTEP(n, 2, 8) BSTEP(n, 4, 4) BSTEP(n, 8, 2) BSTEP(n, 16, 1)
#undef BSTEP
    // lane l now holds element j = bitrev5(l&31) summed over its 32-lane
    // half; fold the two halves of the wave:
    float rap = p[0] + __shfl_xor(p[0], 32);
    float rnd = n[0] + __shfl_xor(n[0], 32);
    if (lane < 32) {
        const int jm = ((lane & 1) << 4) | ((lane & 2) << 2) | (lane & 4) |
                       ((lane & 8) >> 2) | ((lane & 16) >> 4);
        s_wap[wv][jm] = rap;
        s_wnd[wv][jm] = rnd;
    }
    __syncthreads();

    // ---- combine 8 waves; min + hinge in lanes 0-31 of wave 0 ----
    if (t < NS) {
        float ap = 0.f, nd = 0.f;
#pragma unroll
        for (int w = 0; w < 8; ++w) { ap += s_wap[w][t]; nd += s_wnd[w][t]; }
        float an = nd;
#pragma unroll
        for (int m = 1; m < 32; m <<= 1) an = fminf(an, __shfl_xor(an, m));
        float l = fmaxf(ap - an + MARGIN, 0.f);
#pragma unroll
        for (int m = 1; m < 32; m <<= 1) l += __shfl_xor(l, m);
        if (t == 0) cls[c] = l;
    }
}

// Kernel 2: deterministic mean of the 1024 class losses (proven R2 tail).
__global__ __launch_bounds__(256) void ccl_reduce(const float* __restrict__ class_loss,
                                                  float* __restrict__ out) {
    const int t = threadIdx.x;
    float v = class_loss[t] + class_loss[t + 256] + class_loss[t + 512] + class_loss[t + 768];
#pragma unroll
    for (int m = 32; m >= 1; m >>= 1) v += __shfl_down(v, m);
    __shared__ float s_partial[4];
    if ((t & 63) == 0) s_partial[t >> 6] = v;
    __syncthreads();
    if (t == 0)
        out[0] = (s_partial[0] + s_partial[1] + s_partial[2] + s_partial[3]) * (1.f / NC);
}

extern "C" void kernel_launch(void* const* d_in, const int* in_sizes, int n_in,
                              void* d_out, int out_size, void* d_ws, size_t ws_size,
                              hipStream_t stream) {
    const float* emb = (const float*)d_in[0];   // (2*NC*NS, DD) f32
    float* cls = (float*)d_ws;                  // NC per-class losses
    float* out = (float*)d_out;                 // 1 float
    ccl_per_class<<<NC, 512, 0, stream>>>(emb, cls);
    ccl_reduce<<<1, 256, 0, stream>>>(cls, out);
}